// Round 8
// baseline (170.188 us; speedup 1.0000x reference)
//
#include <hip/hip_runtime.h>
#include <hip/hip_bf16.h>
#include <math.h>
#include <stdint.h>

typedef __attribute__((ext_vector_type(8))) short bf16x8;
typedef __attribute__((ext_vector_type(4))) float f32x4;

__device__ __forceinline__ uint32_t pack2(float a, float b) {
    union { __hip_bfloat162 h2; uint32_t u; } c;
    c.h2 = __float22bfloat162_rn(make_float2(a, b));   // v_cvt_pk_bf16_f32
    return c.u;
}
__device__ __forceinline__ unsigned short f2bf(float f) {
    union { __hip_bfloat16 h; unsigned short u; } c;
    c.h = __float2bfloat16(f);
    return c.u;
}
__device__ __forceinline__ float bf2f(unsigned short h) {
    union { uint32_t u; float f; } c; c.u = ((uint32_t)h) << 16;
    return c.f;
}
__device__ __forceinline__ float silu_f(float x) {
    return x / (1.0f + __expf(-x));
}

// Uniform cardinal cubic B-spline bases on grid g_i = -2.2 + 0.4*i.
// Identical to the reference Cox-de-Boor recursion on this uniform grid.
__device__ __forceinline__ void bspline8(float x, float* __restrict__ b) {
    const float tt = (x + 2.2f) * 2.5f;
#pragma unroll
    for (int v = 0; v < 8; ++v) {
        float y = fabsf(tt - (float)(v + 2));
        float p = fmaxf(2.0f - y, 0.0f);
        float q = fmaxf(1.0f - y, 0.0f);
        b[v] = (p * p * p - 4.0f * q * q * q) * (1.0f / 6.0f);
    }
}

// ---------------------------------------------------------------------------
// prep kernels
// ---------------------------------------------------------------------------
__global__ __launch_bounds__(256) void prep_ftw(const float* __restrict__ ftw,
                                                unsigned short* __restrict__ Wb) {
    const int idx = blockIdx.x * 256 + threadIdx.x;   // 98304 = 128*768
    Wb[idx] = f2bf(ftw[idx]);
}

__global__ __launch_bounds__(256) void prep_bp(const float* __restrict__ bw,
                                               const float* __restrict__ sw,
                                               unsigned short* __restrict__ Bp) {
    const int idx = blockIdx.x * 256 + threadIdx.x;   // 524288 = 128*4096
    const int n = idx >> 12;
    const int k = idx & 4095;
    const int f = k >> 4;
    const int v = k & 15;
    float val = 0.f;
    if (v == 0) val = bw[n * 256 + f];
    else if (v <= 8) val = sw[(size_t)(n * 256 + f) * 8 + (v - 1)];
    Bp[idx] = f2bf(val);
}

// ---------------------------------------------------------------------------
// FT GEMM (bf16 MFMA) -- register-direct, NO LDS, NO barriers.
// Each wave independently computes a 32-row x 64-col tile: A fragments
// (fp32, cvt at load) and B fragments (bf16) go global -> VGPR -> MFMA.
// A has zero cross-wave reuse (LDS staging buys nothing); B is L2-resident.
// Latency hiding is pure TLP: free-running waves, no lockstep barriers.
// 2-step software pipeline with NAMED registers (no runtime-indexed arrays).
// Output transposed bf16: HTb[c][r], c = side*128 + col.
// grid (256, 4): y = side*2 + colgroup.  block 256 (4 waves = 4 row-strips).
// ---------------------------------------------------------------------------
__global__ __launch_bounds__(256) void ft_mfma(
        const float* __restrict__ stm, const float* __restrict__ nstm,
        const unsigned short* __restrict__ Wb, const float* __restrict__ bias,
        unsigned short* __restrict__ HTb) {
    const int side = blockIdx.y >> 1;
    const int cg = blockIdx.y & 1;
    const float* __restrict__ A = side ? nstm : stm;
    const int t = threadIdx.x;
    const int lane = t & 63, wid = t >> 6;
    const int fr = lane & 15;
    const int h = lane >> 4;                 // 0..3
    const int r0 = blockIdx.x * 128 + wid * 32;
    const int c0 = cg * 64;

    // per-lane fragment base pointers (k-offset h*8 baked in)
    const float* __restrict__ pa0 = &A[(size_t)(r0 + fr) * 768 + h * 8];
    const float* __restrict__ pa1 = &A[(size_t)(r0 + 16 + fr) * 768 + h * 8];
    const unsigned short* __restrict__ pb0 = &Wb[(size_t)(c0 + fr) * 768 + h * 8];
    const unsigned short* __restrict__ pb1 = pb0 + (size_t)16 * 768;
    const unsigned short* __restrict__ pb2 = pb0 + (size_t)32 * 768;
    const unsigned short* __restrict__ pb3 = pb0 + (size_t)48 * 768;

    float4 xa00, xa01, xa10, xa11;   // stage X: A frags (2 rows-tiles x 2 f4)
    int4 xb0, xb1, xb2, xb3;         // stage X: B frags
    float4 ya00, ya01, ya10, ya11;   // stage Y
    int4 yb0, yb1, yb2, yb3;

#define FT_LOADX(ks)                                                       \
    {                                                                      \
        const int o = (ks) * 32;                                           \
        xa00 = *reinterpret_cast<const float4*>(pa0 + o);                  \
        xa01 = *reinterpret_cast<const float4*>(pa0 + o + 4);              \
        xa10 = *reinterpret_cast<const float4*>(pa1 + o);                  \
        xa11 = *reinterpret_cast<const float4*>(pa1 + o + 4);              \
        xb0 = *reinterpret_cast<const int4*>(pb0 + o);                     \
        xb1 = *reinterpret_cast<const int4*>(pb1 + o);                     \
        xb2 = *reinterpret_cast<const int4*>(pb2 + o);                     \
        xb3 = *reinterpret_cast<const int4*>(pb3 + o);                     \
    }
#define FT_LOADY(ks)                                                       \
    {                                                                      \
        const int o = (ks) * 32;                                           \
        ya00 = *reinterpret_cast<const float4*>(pa0 + o);                  \
        ya01 = *reinterpret_cast<const float4*>(pa0 + o + 4);              \
        ya10 = *reinterpret_cast<const float4*>(pa1 + o);                  \
        ya11 = *reinterpret_cast<const float4*>(pa1 + o + 4);              \
        yb0 = *reinterpret_cast<const int4*>(pb0 + o);                     \
        yb1 = *reinterpret_cast<const int4*>(pb1 + o);                     \
        yb2 = *reinterpret_cast<const int4*>(pb2 + o);                     \
        yb3 = *reinterpret_cast<const int4*>(pb3 + o);                     \
    }

    f32x4 acc[2][4];
#pragma unroll
    for (int mt = 0; mt < 2; ++mt)
#pragma unroll
        for (int nt = 0; nt < 4; ++nt) acc[mt][nt] = (f32x4){0.f, 0.f, 0.f, 0.f};

#define FT_STEP(A00, A01, A10, A11, B0, B1, B2, B3)                        \
    {                                                                      \
        union { bf16x8 v; uint32_t u[4]; } c0v, c1v;                       \
        union { bf16x8 v; int4 w; } b0v, b1v, b2v, b3v;                    \
        c0v.u[0] = pack2(A00.x, A00.y); c0v.u[1] = pack2(A00.z, A00.w);    \
        c0v.u[2] = pack2(A01.x, A01.y); c0v.u[3] = pack2(A01.z, A01.w);    \
        c1v.u[0] = pack2(A10.x, A10.y); c1v.u[1] = pack2(A10.z, A10.w);    \
        c1v.u[2] = pack2(A11.x, A11.y); c1v.u[3] = pack2(A11.z, A11.w);    \
        b0v.w = B0; b1v.w = B1; b2v.w = B2; b3v.w = B3;                    \
        acc[0][0] = __builtin_amdgcn_mfma_f32_16x16x32_bf16(               \
            c0v.v, b0v.v, acc[0][0], 0, 0, 0);                             \
        acc[0][1] = __builtin_amdgcn_mfma_f32_16x16x32_bf16(               \
            c0v.v, b1v.v, acc[0][1], 0, 0, 0);                             \
        acc[0][2] = __builtin_amdgcn_mfma_f32_16x16x32_bf16(               \
            c0v.v, b2v.v, acc[0][2], 0, 0, 0);                             \
        acc[0][3] = __builtin_amdgcn_mfma_f32_16x16x32_bf16(               \
            c0v.v, b3v.v, acc[0][3], 0, 0, 0);                             \
        acc[1][0] = __builtin_amdgcn_mfma_f32_16x16x32_bf16(               \
            c1v.v, b0v.v, acc[1][0], 0, 0, 0);                             \
        acc[1][1] = __builtin_amdgcn_mfma_f32_16x16x32_bf16(               \
            c1v.v, b1v.v, acc[1][1], 0, 0, 0);                             \
        acc[1][2] = __builtin_amdgcn_mfma_f32_16x16x32_bf16(               \
            c1v.v, b2v.v, acc[1][2], 0, 0, 0);                             \
        acc[1][3] = __builtin_amdgcn_mfma_f32_16x16x32_bf16(               \
            c1v.v, b3v.v, acc[1][3], 0, 0, 0);                             \
    }

    // 24 K-steps, 2-deep register pipeline
    FT_LOADX(0);
#pragma unroll 1
    for (int kp = 0; kp < 12; ++kp) {
        FT_LOADY(2 * kp + 1);
        FT_STEP(xa00, xa01, xa10, xa11, xb0, xb1, xb2, xb3);
        if (kp < 11) FT_LOADX(2 * kp + 2);
        FT_STEP(ya00, ya01, ya10, ya11, yb0, yb1, yb2, yb3);
    }

    // epilogue: HTb[c][r] bf16, int2 over 4 consecutive rows
#pragma unroll
    for (int nt = 0; nt < 4; ++nt) {
        const int colL = c0 + nt * 16 + fr;
        const float bv = bias[colL];
        const size_t cgo = (size_t)(side * 128 + colL) * 32768;
#pragma unroll
        for (int mt = 0; mt < 2; ++mt) {
            const int row = r0 + mt * 16 + h * 4;
            int2 o;
            o.x = (int)pack2(acc[mt][nt][0] + bv, acc[mt][nt][1] + bv);
            o.y = (int)pack2(acc[mt][nt][2] + bv, acc[mt][nt][3] + bv);
            *reinterpret_cast<int2*>(&HTb[cgo + row]) = o;
        }
    }
}

// ---------------------------------------------------------------------------
// KAN1 (bf16 MFMA, expanded A, K=256*16) + fused KAN2 + sigmoid.
// BM=64, K-step=128 (8 features), block 512 (8 waves as 2x4; wave 32x32).
// grid 512 -> 2 blocks/CU, 16 waves/CU.
// ---------------------------------------------------------------------------
__global__ __launch_bounds__(512) void kan1_fused(
        const unsigned short* __restrict__ HTb, // 256 x 32768 bf16 (transposed)
        const unsigned short* __restrict__ Bp,  // 128 x 4096 bf16 (padded)
        const float* __restrict__ w2b,          // 128
        const float* __restrict__ w2s,          // 128 x 8
        float* __restrict__ out) {              // 32768
    __shared__ alignas(16) char lds[49152];   // smP 16 KB | smB 32 KB ; epi: smH
    char* smP = lds;
    char* smB = lds + 16384;
    unsigned short* smH = (unsigned short*)lds;
    const int r0 = blockIdx.x * 64;
    const int t = threadIdx.x;
    const int lane = t & 63, wid = t >> 6;
    const int wr = wid >> 2, wc = wid & 3;     // 2 x 4 waves; wave tile 32x32
    const int fr = lane & 15;
    const int h = lane >> 4;
    const int fkb = h * 8;

    const int xrow = t & 63, xf = t >> 6;      // 1 expansion per thread
    const int bn = t >> 2, bk0 = (t & 3) * 32; // B: 64 B contiguous per thread

    f32x4 acc[2][2];
#pragma unroll
    for (int mt = 0; mt < 2; ++mt)
#pragma unroll
        for (int nt = 0; nt < 2; ++nt) acc[mt][nt] = (f32x4){0.f, 0.f, 0.f, 0.f};

    for (int jb = 0; jb < 256; jb += 8) {
        // expand phi: one (row, feature) pair per thread, coalesced bf16 read
        {
            const float x = bf2f(HTb[(size_t)(jb + xf) * 32768 + r0 + xrow]);
            float bs[8];
            bspline8(x, bs);
            const uint32_t w0 = pack2(silu_f(x), bs[0]);
            const uint32_t w1 = pack2(bs[1], bs[2]);
            const uint32_t w2 = pack2(bs[3], bs[4]);
            const uint32_t w3 = pack2(bs[5], bs[6]);
            const uint32_t w4 = pack2(bs[7], 0.f);
            const uint32_t swz = (uint32_t)(xrow & 15) << 4;
            const uint32_t base = (uint32_t)xrow * 256u + (uint32_t)xf * 32u;
            *reinterpret_cast<int4*>(smP + (base ^ swz)) =
                make_int4((int)w0, (int)w1, (int)w2, (int)w3);
            *reinterpret_cast<int4*>(smP + ((base + 16u) ^ swz)) =
                make_int4((int)w4, 0, 0, 0);
        }
        // stage B tile: 4x int4 per thread
        {
            const int4* bgp = reinterpret_cast<const int4*>(
                &Bp[(size_t)bn * 4096 + jb * 16 + bk0]);
#pragma unroll
            for (int q = 0; q < 4; ++q) {
                int4 w = bgp[q];
                uint32_t off = ((uint32_t)bn * 256u +
                                (uint32_t)(bk0 + q * 8) * 2u) ^
                               ((uint32_t)(bn & 15) << 4);
                *reinterpret_cast<int4*>(smB + off) = w;
            }
        }
        __syncthreads();
        __builtin_amdgcn_s_setprio(1);
#pragma unroll
        for (int ks = 0; ks < 4; ++ks) {
            const int kb = ks * 32 + fkb;
            bf16x8 a[2], b[2];
#pragma unroll
            for (int mt = 0; mt < 2; ++mt) {
                uint32_t row = (uint32_t)(wr * 32 + mt * 16 + fr);
                uint32_t off = (row * 256u + (uint32_t)kb * 2u) ^ ((row & 15u) << 4);
                a[mt] = *reinterpret_cast<const bf16x8*>(smP + off);
            }
#pragma unroll
            for (int nt = 0; nt < 2; ++nt) {
                uint32_t n = (uint32_t)(wc * 32 + nt * 16 + fr);
                uint32_t off = (n * 256u + (uint32_t)kb * 2u) ^ ((n & 15u) << 4);
                b[nt] = *reinterpret_cast<const bf16x8*>(smB + off);
            }
#pragma unroll
            for (int mt = 0; mt < 2; ++mt)
#pragma unroll
                for (int nt = 0; nt < 2; ++nt)
                    acc[mt][nt] = __builtin_amdgcn_mfma_f32_16x16x32_bf16(
                        a[mt], b[nt], acc[mt][nt], 0, 0, 0);
        }
        __builtin_amdgcn_s_setprio(0);
        __syncthreads();
    }
    // stash H2 tile (bf16) into LDS [64][136]
#pragma unroll
    for (int mt = 0; mt < 2; ++mt)
#pragma unroll
        for (int nt = 0; nt < 2; ++nt) {
            const int col = wc * 32 + nt * 16 + fr;
#pragma unroll
            for (int j = 0; j < 4; ++j) {
                const int row = wr * 32 + mt * 16 + h * 4 + j;
                smH[row * 136 + col] = f2bf(acc[mt][nt][j]);
            }
        }
    __syncthreads();
    // fused KAN2: 8 threads per row, 16 cols each, shfl reduce, sigmoid
    const int row = t >> 3, qd = t & 7;
    float sum = 0.f;
#pragma unroll 4
    for (int i = 0; i < 16; ++i) {
        const int j = qd * 16 + ((i + qd * 2) & 15);   // stagger banks
        const float x = bf2f(smH[row * 136 + j]);
        float bs[8];
        bspline8(x, bs);
        const float4 s0 = *reinterpret_cast<const float4*>(&w2s[j * 8]);
        const float4 s1 = *reinterpret_cast<const float4*>(&w2s[j * 8 + 4]);
        float s = silu_f(x) * w2b[j];
        s += bs[0] * s0.x + bs[1] * s0.y + bs[2] * s0.z + bs[3] * s0.w;
        s += bs[4] * s1.x + bs[5] * s1.y + bs[6] * s1.z + bs[7] * s1.w;
        sum += s;
    }
    sum += __shfl_xor(sum, 1, 64);
    sum += __shfl_xor(sum, 2, 64);
    sum += __shfl_xor(sum, 4, 64);
    if (qd == 0) out[r0 + row] = 1.0f / (1.0f + __expf(-sum));
}

// ---------------------------------------------------------------------------
extern "C" void kernel_launch(void* const* d_in, const int* in_sizes, int n_in,
                              void* d_out, int out_size, void* d_ws, size_t ws_size,
                              hipStream_t stream) {
    const float* stm  = (const float*)d_in[0];
    const float* nstm = (const float*)d_in[1];
    const float* ft_w = (const float*)d_in[2];
    const float* ft_b = (const float*)d_in[3];
    const float* k1bw = (const float*)d_in[4];
    const float* k1sw = (const float*)d_in[5];
    const float* k2bw = (const float*)d_in[6];
    const float* k2sw = (const float*)d_in[7];
    float* out = (float*)d_out;

    char* ws = (char*)d_ws;
    unsigned short* HTb = (unsigned short*)ws;                        // 16,777,216 B
    unsigned short* Wb  = (unsigned short*)(ws + 16777216);           //    196,608 B
    unsigned short* Bp  = (unsigned short*)(ws + 16777216 + 196608);  //  1,048,576 B

    prep_ftw<<<384, 256, 0, stream>>>(ft_w, Wb);
    prep_bp<<<2048, 256, 0, stream>>>(k1bw, k1sw, Bp);
    ft_mfma<<<dim3(256, 4), 256, 0, stream>>>(stm, nstm, Wb, ft_b, HTb);
    kan1_fused<<<512, 512, 0, stream>>>(HTb, Bp, k2bw, k2sw, out);
}

// Round 9
// 131.382 us; speedup vs baseline: 1.2954x; 1.2954x over previous
//
#include <hip/hip_runtime.h>
#include <hip/hip_bf16.h>
#include <math.h>
#include <stdint.h>

typedef __attribute__((ext_vector_type(8))) short bf16x8;
typedef __attribute__((ext_vector_type(4))) float f32x4;

__device__ __forceinline__ uint32_t pack2(float a, float b) {
    union { __hip_bfloat162 h2; uint32_t u; } c;
    c.h2 = __float22bfloat162_rn(make_float2(a, b));   // v_cvt_pk_bf16_f32
    return c.u;
}
__device__ __forceinline__ unsigned short f2bf(float f) {
    union { __hip_bfloat16 h; unsigned short u; } c;
    c.h = __float2bfloat16(f);
    return c.u;
}
__device__ __forceinline__ float bf2f(unsigned short h) {
    union { uint32_t u; float f; } c; c.u = ((uint32_t)h) << 16;
    return c.f;
}
__device__ __forceinline__ float silu_f(float x) {
    return x / (1.0f + __expf(-x));
}

// Uniform cardinal cubic B-spline bases on grid g_i = -2.2 + 0.4*i.
// Identical to the reference Cox-de-Boor recursion on this uniform grid.
__device__ __forceinline__ void bspline8(float x, float* __restrict__ b) {
    const float tt = (x + 2.2f) * 2.5f;
#pragma unroll
    for (int v = 0; v < 8; ++v) {
        float y = fabsf(tt - (float)(v + 2));
        float p = fmaxf(2.0f - y, 0.0f);
        float q = fmaxf(1.0f - y, 0.0f);
        b[v] = (p * p * p - 4.0f * q * q * q) * (1.0f / 6.0f);
    }
}

__device__ __forceinline__ void gload16(const void* g, void* l) {
    __builtin_amdgcn_global_load_lds(
        (const __attribute__((address_space(1))) void*)g,
        (__attribute__((address_space(3))) void*)l, 16, 0, 0);
}

// ---------------------------------------------------------------------------
// prep kernels
// ---------------------------------------------------------------------------
__global__ __launch_bounds__(256) void prep_ftw(const float* __restrict__ ftw,
                                                unsigned short* __restrict__ Wb) {
    const int idx = blockIdx.x * 256 + threadIdx.x;   // 98304 = 128*768
    Wb[idx] = f2bf(ftw[idx]);
}

__global__ __launch_bounds__(256) void prep_bp(const float* __restrict__ bw,
                                               const float* __restrict__ sw,
                                               unsigned short* __restrict__ Bp) {
    const int idx = blockIdx.x * 256 + threadIdx.x;   // 524288 = 128*4096
    const int n = idx >> 12;
    const int k = idx & 4095;
    const int f = k >> 4;
    const int v = k & 15;
    float val = 0.f;
    if (v == 0) val = bw[n * 256 + f];
    else if (v <= 8) val = sw[(size_t)(n * 256 + f) * 8 + (v - 1)];
    Bp[idx] = f2bf(val);
}

// ---------------------------------------------------------------------------
// FT GEMM (bf16 MFMA), BM=128, BK=256 (3 K-tiles), block 512 (8 waves 4x2;
// wave tile 32 rows x 64 cols).  A staging = PURE MEMCPY pattern: one row's
// 1-KB window per global_load_dwordx4 (consecutive lanes -> consecutive
// addresses), 16 loads in flight per wave (128 KB outstanding/CU), cvt to
// bf16 in-reg, ds_write_b64 into chunk-swizzled LDS.  B via global_load_lds
// (linear dest + inverse-swizzled source, rule 21).  LDS 128 KB single buf.
// Output transposed bf16: HTb[c][r], c = side*128 + col.  grid (256, 2).
// ---------------------------------------------------------------------------
__global__ __launch_bounds__(512) void ft_mfma(
        const float* __restrict__ stm, const float* __restrict__ nstm,
        const unsigned short* __restrict__ Wb, const float* __restrict__ bias,
        unsigned short* __restrict__ HTb) {
    __shared__ alignas(16) char lds[131072];  // smA 64 KB | smB 64 KB
    char* smA = lds;
    char* smB = lds + 65536;
    const int side = blockIdx.y;
    const float* __restrict__ A = side ? nstm : stm;
    const int r0 = blockIdx.x * 128;
    const int t = threadIdx.x;
    const int lane = t & 63, wid = t >> 6;
    const int wr = wid >> 1, wc = wid & 1;    // 4 x 2 waves; wave 32r x 64c
    const int fr = lane & 15;
    const int h = lane >> 4;                  // 0..3
    const int sw = fr & 7;                    // read-side chunk swizzle key

    f32x4 acc[2][4];
#pragma unroll
    for (int mt = 0; mt < 2; ++mt)
#pragma unroll
        for (int nt = 0; nt < 4; ++nt) acc[mt][nt] = (f32x4){0.f, 0.f, 0.f, 0.f};

#pragma unroll 1
    for (int tile = 0; tile < 3; ++tile) {
        const int k0 = tile * 256;
        // ---- stage A: 16 contiguous 1-KB row-window loads per wave ----
        float4 av[16];
#pragma unroll
        for (int i = 0; i < 16; ++i) {
            const int row = wid * 16 + i;
            av[i] = *reinterpret_cast<const float4*>(
                &A[(size_t)(r0 + row) * 768 + k0 + lane * 4]);
        }
        // ---- stage B: 8 global_load_lds per wave (1 KB each, 2 cols) ----
#pragma unroll
        for (int j = 0; j < 8; ++j) {
            const int idx = wid * 8 + j;              // 0..63
            const int col = idx * 2 + (lane >> 5);
            const unsigned short* src =
                &Wb[(size_t)col * 768 + k0 + (((lane & 31) ^ (col & 7)) << 3)];
            gload16(src, smB + idx * 1024);
        }
        // ---- cvt + swizzled ds_write of A (drains loads in order) ----
#pragma unroll
        for (int i = 0; i < 16; ++i) {
            const int row = wid * 16 + i;
            int2 wv;
            wv.x = (int)pack2(av[i].x, av[i].y);
            wv.y = (int)pack2(av[i].z, av[i].w);
            const uint32_t dst = (uint32_t)row * 512u +
                ((uint32_t)((lane >> 1) ^ (i & 7)) << 4) + (uint32_t)(lane & 1) * 8u;
            *reinterpret_cast<int2*>(smA + dst) = wv;
        }
        asm volatile("s_waitcnt vmcnt(0) lgkmcnt(0)" ::: "memory");
        __builtin_amdgcn_s_barrier();
        // ---- compute: 8 K-steps of 32 ----
#pragma unroll
        for (int ks = 0; ks < 8; ++ks) {
            const uint32_t ch = (uint32_t)(ks * 4 + h);
            bf16x8 a[2], b[4];
#pragma unroll
            for (int mt = 0; mt < 2; ++mt) {
                const uint32_t row = (uint32_t)(wr * 32 + mt * 16 + fr);
                a[mt] = *reinterpret_cast<const bf16x8*>(
                    smA + row * 512u + ((ch ^ (uint32_t)sw) << 4));
            }
#pragma unroll
            for (int nt = 0; nt < 4; ++nt) {
                const uint32_t col = (uint32_t)(wc * 64 + nt * 16 + fr);
                b[nt] = *reinterpret_cast<const bf16x8*>(
                    smB + col * 512u + ((ch ^ (uint32_t)sw) << 4));
            }
#pragma unroll
            for (int mt = 0; mt < 2; ++mt)
#pragma unroll
                for (int nt = 0; nt < 4; ++nt)
                    acc[mt][nt] = __builtin_amdgcn_mfma_f32_16x16x32_bf16(
                        a[mt], b[nt], acc[mt][nt], 0, 0, 0);
        }
        asm volatile("s_waitcnt lgkmcnt(0)" ::: "memory");
        __builtin_amdgcn_s_barrier();
    }

    // epilogue: HTb[c][r] bf16, int2 over 4 consecutive rows
#pragma unroll
    for (int nt = 0; nt < 4; ++nt) {
        const int colL = wc * 64 + nt * 16 + fr;
        const float bv = bias[colL];
        const size_t cgo = (size_t)(side * 128 + colL) * 32768;
#pragma unroll
        for (int mt = 0; mt < 2; ++mt) {
            const int row = r0 + wr * 32 + mt * 16 + h * 4;
            int2 o;
            o.x = (int)pack2(acc[mt][nt][0] + bv, acc[mt][nt][1] + bv);
            o.y = (int)pack2(acc[mt][nt][2] + bv, acc[mt][nt][3] + bv);
            *reinterpret_cast<int2*>(&HTb[cgo + row]) = o;
        }
    }
}

// ---------------------------------------------------------------------------
// KAN1 (bf16 MFMA, expanded A, K=256*16) + fused KAN2 + sigmoid.
// BM=64, K-step=128 (8 features), block 512 (8 waves as 2x4; wave 32x32).
// grid 512 -> 2-3 blocks/CU, 16+ waves/CU.  (Unchanged from round 7.)
// ---------------------------------------------------------------------------
__global__ __launch_bounds__(512) void kan1_fused(
        const unsigned short* __restrict__ HTb, // 256 x 32768 bf16 (transposed)
        const unsigned short* __restrict__ Bp,  // 128 x 4096 bf16 (padded)
        const float* __restrict__ w2b,          // 128
        const float* __restrict__ w2s,          // 128 x 8
        float* __restrict__ out) {              // 32768
    __shared__ alignas(16) char lds[49152];   // smP 16 KB | smB 32 KB ; epi: smH
    char* smP = lds;
    char* smB = lds + 16384;
    unsigned short* smH = (unsigned short*)lds;
    const int r0 = blockIdx.x * 64;
    const int t = threadIdx.x;
    const int lane = t & 63, wid = t >> 6;
    const int wr = wid >> 2, wc = wid & 3;     // 2 x 4 waves; wave tile 32x32
    const int fr = lane & 15;
    const int h = lane >> 4;
    const int fkb = h * 8;

    const int xrow = t & 63, xf = t >> 6;      // 1 expansion per thread
    const int bn = t >> 2, bk0 = (t & 3) * 32; // B: 64 B contiguous per thread

    f32x4 acc[2][2];
#pragma unroll
    for (int mt = 0; mt < 2; ++mt)
#pragma unroll
        for (int nt = 0; nt < 2; ++nt) acc[mt][nt] = (f32x4){0.f, 0.f, 0.f, 0.f};

    for (int jb = 0; jb < 256; jb += 8) {
        // expand phi: one (row, feature) pair per thread, coalesced bf16 read
        {
            const float x = bf2f(HTb[(size_t)(jb + xf) * 32768 + r0 + xrow]);
            float bs[8];
            bspline8(x, bs);
            const uint32_t w0 = pack2(silu_f(x), bs[0]);
            const uint32_t w1 = pack2(bs[1], bs[2]);
            const uint32_t w2 = pack2(bs[3], bs[4]);
            const uint32_t w3 = pack2(bs[5], bs[6]);
            const uint32_t w4 = pack2(bs[7], 0.f);
            const uint32_t swz = (uint32_t)(xrow & 15) << 4;
            const uint32_t base = (uint32_t)xrow * 256u + (uint32_t)xf * 32u;
            *reinterpret_cast<int4*>(smP + (base ^ swz)) =
                make_int4((int)w0, (int)w1, (int)w2, (int)w3);
            *reinterpret_cast<int4*>(smP + ((base + 16u) ^ swz)) =
                make_int4((int)w4, 0, 0, 0);
        }
        // stage B tile: 4x int4 per thread
        {
            const int4* bgp = reinterpret_cast<const int4*>(
                &Bp[(size_t)bn * 4096 + jb * 16 + bk0]);
#pragma unroll
            for (int q = 0; q < 4; ++q) {
                int4 w = bgp[q];
                uint32_t off = ((uint32_t)bn * 256u +
                                (uint32_t)(bk0 + q * 8) * 2u) ^
                               ((uint32_t)(bn & 15) << 4);
                *reinterpret_cast<int4*>(smB + off) = w;
            }
        }
        __syncthreads();
        __builtin_amdgcn_s_setprio(1);
#pragma unroll
        for (int ks = 0; ks < 4; ++ks) {
            const int kb = ks * 32 + fkb;
            bf16x8 a[2], b[2];
#pragma unroll
            for (int mt = 0; mt < 2; ++mt) {
                uint32_t row = (uint32_t)(wr * 32 + mt * 16 + fr);
                uint32_t off = (row * 256u + (uint32_t)kb * 2u) ^ ((row & 15u) << 4);
                a[mt] = *reinterpret_cast<const bf16x8*>(smP + off);
            }
#pragma unroll
            for (int nt = 0; nt < 2; ++nt) {
                uint32_t n = (uint32_t)(wc * 32 + nt * 16 + fr);
                uint32_t off = (n * 256u + (uint32_t)kb * 2u) ^ ((n & 15u) << 4);
                b[nt] = *reinterpret_cast<const bf16x8*>(smB + off);
            }
#pragma unroll
            for (int mt = 0; mt < 2; ++mt)
#pragma unroll
                for (int nt = 0; nt < 2; ++nt)
                    acc[mt][nt] = __builtin_amdgcn_mfma_f32_16x16x32_bf16(
                        a[mt], b[nt], acc[mt][nt], 0, 0, 0);
        }
        __builtin_amdgcn_s_setprio(0);
        __syncthreads();
    }
    // stash H2 tile (bf16) into LDS [64][136]
#pragma unroll
    for (int mt = 0; mt < 2; ++mt)
#pragma unroll
        for (int nt = 0; nt < 2; ++nt) {
            const int col = wc * 32 + nt * 16 + fr;
#pragma unroll
            for (int j = 0; j < 4; ++j) {
                const int row = wr * 32 + mt * 16 + h * 4 + j;
                smH[row * 136 + col] = f2bf(acc[mt][nt][j]);
            }
        }
    __syncthreads();
    // fused KAN2: 8 threads per row, 16 cols each, shfl reduce, sigmoid
    const int row = t >> 3, qd = t & 7;
    float sum = 0.f;
#pragma unroll 4
    for (int i = 0; i < 16; ++i) {
        const int j = qd * 16 + ((i + qd * 2) & 15);   // stagger banks
        const float x = bf2f(smH[row * 136 + j]);
        float bs[8];
        bspline8(x, bs);
        const float4 s0 = *reinterpret_cast<const float4*>(&w2s[j * 8]);
        const float4 s1 = *reinterpret_cast<const float4*>(&w2s[j * 8 + 4]);
        float s = silu_f(x) * w2b[j];
        s += bs[0] * s0.x + bs[1] * s0.y + bs[2] * s0.z + bs[3] * s0.w;
        s += bs[4] * s1.x + bs[5] * s1.y + bs[6] * s1.z + bs[7] * s1.w;
        sum += s;
    }
    sum += __shfl_xor(sum, 1, 64);
    sum += __shfl_xor(sum, 2, 64);
    sum += __shfl_xor(sum, 4, 64);
    if (qd == 0) out[r0 + row] = 1.0f / (1.0f + __expf(-sum));
}

// ---------------------------------------------------------------------------
extern "C" void kernel_launch(void* const* d_in, const int* in_sizes, int n_in,
                              void* d_out, int out_size, void* d_ws, size_t ws_size,
                              hipStream_t stream) {
    const float* stm  = (const float*)d_in[0];
    const float* nstm = (const float*)d_in[1];
    const float* ft_w = (const float*)d_in[2];
    const float* ft_b = (const float*)d_in[3];
    const float* k1bw = (const float*)d_in[4];
    const float* k1sw = (const float*)d_in[5];
    const float* k2bw = (const float*)d_in[6];
    const float* k2sw = (const float*)d_in[7];
    float* out = (float*)d_out;

    char* ws = (char*)d_ws;
    unsigned short* HTb = (unsigned short*)ws;                        // 16,777,216 B
    unsigned short* Wb  = (unsigned short*)(ws + 16777216);           //    196,608 B
    unsigned short* Bp  = (unsigned short*)(ws + 16777216 + 196608);  //  1,048,576 B

    prep_ftw<<<384, 256, 0, stream>>>(ft_w, Wb);
    prep_bp<<<2048, 256, 0, stream>>>(k1bw, k1sw, Bp);
    ft_mfma<<<dim3(256, 2), 512, 0, stream>>>(stm, nstm, Wb, ft_b, HTb);
    kan1_fused<<<512, 512, 0, stream>>>(HTb, Bp, k2bw, k2sw, out);
}

// Round 10
// 115.608 us; speedup vs baseline: 1.4721x; 1.1364x over previous
//
#include <hip/hip_runtime.h>
#include <hip/hip_bf16.h>
#include <math.h>
#include <stdint.h>

typedef __attribute__((ext_vector_type(8))) short bf16x8;
typedef __attribute__((ext_vector_type(4))) float f32x4;

#define SH 260   // smH stride in shorts (padded: 520 B row -> 2-way-ish banks)

__device__ __forceinline__ uint32_t pack2(float a, float b) {
    union { __hip_bfloat162 h2; uint32_t u; } c;
    c.h2 = __float22bfloat162_rn(make_float2(a, b));   // v_cvt_pk_bf16_f32
    return c.u;
}
__device__ __forceinline__ unsigned short f2bf(float f) {
    union { __hip_bfloat16 h; unsigned short u; } c;
    c.h = __float2bfloat16(f);
    return c.u;
}
__device__ __forceinline__ float bf2f(unsigned short h) {
    union { uint32_t u; float f; } c; c.u = ((uint32_t)h) << 16;
    return c.f;
}
__device__ __forceinline__ float silu_f(float x) {
    return x / (1.0f + __expf(-x));
}

// Uniform cardinal cubic B-spline bases on grid g_i = -2.2 + 0.4*i.
// Identical to the reference Cox-de-Boor recursion on this uniform grid.
__device__ __forceinline__ void bspline8(float x, float* __restrict__ b) {
    const float tt = (x + 2.2f) * 2.5f;
#pragma unroll
    for (int v = 0; v < 8; ++v) {
        float y = fabsf(tt - (float)(v + 2));
        float p = fmaxf(2.0f - y, 0.0f);
        float q = fmaxf(1.0f - y, 0.0f);
        b[v] = (p * p * p - 4.0f * q * q * q) * (1.0f / 6.0f);
    }
}

__device__ __forceinline__ void gload16(const void* g, void* l) {
    __builtin_amdgcn_global_load_lds(
        (const __attribute__((address_space(1))) void*)g,
        (__attribute__((address_space(3))) void*)l, 16, 0, 0);
}

// ---------------------------------------------------------------------------
// prep kernels
// ---------------------------------------------------------------------------
__global__ __launch_bounds__(256) void prep_ftw(const float* __restrict__ ftw,
                                                unsigned short* __restrict__ Wb) {
    const int idx = blockIdx.x * 256 + threadIdx.x;   // 98304 = 128*768
    Wb[idx] = f2bf(ftw[idx]);
}

__global__ __launch_bounds__(256) void prep_bp(const float* __restrict__ bw,
                                               const float* __restrict__ sw,
                                               unsigned short* __restrict__ Bp) {
    const int idx = blockIdx.x * 256 + threadIdx.x;   // 524288 = 128*4096
    const int n = idx >> 12;
    const int k = idx & 4095;
    const int f = k >> 4;
    const int v = k & 15;
    float val = 0.f;
    if (v == 0) val = bw[n * 256 + f];
    else if (v <= 8) val = sw[(size_t)(n * 256 + f) * 8 + (v - 1)];
    Bp[idx] = f2bf(val);
}

// ---------------------------------------------------------------------------
// FUSED: per 128-row tile ->
//   Phase 1: H[:, 0:128] = silu-less GEMM(stm, ftw)+b ; H[:,128:256] (nstm)
//            BK=128, 12 K-tiles, A reg-prefetched 1 tile ahead (counted
//            vmcnt(8)), Wb via gload_lds (pre-swizzled source, rule 21).
//            H kept ONLY in LDS (128 x 256 bf16, stride 260).
//   Phase 2: KAN1 expanded-A GEMM, 32 jb-steps: Bp gload_lds issued first
//            (L2 latency hides under ~180-op expansion VALU), phi + Bp in
//            chunk-XOR-swizzled LDS, 32 MFMA per wave per step.
//   Phase 3: KAN2 per-row reduce + sigmoid.
// grid 256 (1 block/CU), block 512 (8 waves).  LDS 129 KB.
// ---------------------------------------------------------------------------
__global__ __launch_bounds__(512) void kan_fused(
        const float* __restrict__ stm, const float* __restrict__ nstm,
        const unsigned short* __restrict__ Wb, const float* __restrict__ bias,
        const unsigned short* __restrict__ Bp,
        const float* __restrict__ w2b, const float* __restrict__ w2s,
        float* __restrict__ out) {
    __shared__ alignas(16) char lds[132096];     // smA 32K | smB 32K | smH 66.5K
    char* smA = lds;
    char* smB = lds + 32768;
    unsigned short* smH = (unsigned short*)(lds + 65536);

    const int r0 = blockIdx.x * 128;
    const int t = threadIdx.x;
    const int l = t & 63, w = t >> 6;
    const int fr = l & 15, h = l >> 4;

    // ================= Phase 1: feature transform ==========================
    const int wrF = w >> 1, wcF = w & 1;          // 4x2 wave grid (32r x 64c)
    const int arowb = w * 16 + (l >> 5);          // A rows: + q*2
    const int acol = (l & 31) * 4;                // float index in 128-window

    float4 regY[8];
    f32x4 facc[2][4];
#pragma unroll
    for (int mt = 0; mt < 2; ++mt)
#pragma unroll
        for (int nt = 0; nt < 4; ++nt) facc[mt][nt] = (f32x4){0.f, 0.f, 0.f, 0.f};

    // prologue: A tile 0 -> regs
#pragma unroll
    for (int q = 0; q < 8; ++q)
        regY[q] = *reinterpret_cast<const float4*>(
            &stm[(size_t)(r0 + arowb + q * 2) * 768 + acol]);

#pragma unroll 1
    for (int tk = 0; tk < 12; ++tk) {
        const int k0 = (tk >= 6 ? tk - 6 : tk) * 128;
        // 1. cvt + swizzled ds_write of A tile tk (regY)
#pragma unroll
        for (int q = 0; q < 8; ++q) {
            const int rowA = arowb + q * 2;
            int2 wv;
            wv.x = (int)pack2(regY[q].x, regY[q].y);
            wv.y = (int)pack2(regY[q].z, regY[q].w);
            const uint32_t dst = (uint32_t)rowA * 256u +
                ((uint32_t)((((l & 31) >> 1)) ^ (rowA & 15)) << 4) +
                (uint32_t)(l & 1) * 8u;
            *reinterpret_cast<int2*>(smA + dst) = wv;
        }
        // 2. Wb tile via gload_lds (linear dest, pre-swizzled source)
#pragma unroll
        for (int j = 0; j < 4; ++j) {
            const int idx = w * 4 + j;
            const int col = idx * 4 + (l >> 4);
            gload16(&Wb[(size_t)col * 768 + k0 + (((l & 15) ^ (col & 15)) << 3)],
                    smB + idx * 1024);
        }
        // 3. prefetch A tile tk+1 (stays in flight across barrier + compute)
        if (tk < 11) {
            const int nk = tk + 1;
            const float* __restrict__ Ap = (nk >= 6) ? nstm : stm;
            const int nk0 = (nk >= 6 ? nk - 6 : nk) * 128;
#pragma unroll
            for (int q = 0; q < 8; ++q)
                regY[q] = *reinterpret_cast<const float4*>(
                    &Ap[(size_t)(r0 + arowb + q * 2) * 768 + nk0 + acol]);
            asm volatile("s_waitcnt vmcnt(8)" ::: "memory");  // Wb done; A flying
        } else {
            asm volatile("s_waitcnt vmcnt(0)" ::: "memory");
        }
        asm volatile("s_waitcnt lgkmcnt(0)" ::: "memory");
        __builtin_amdgcn_sched_barrier(0);
        __builtin_amdgcn_s_barrier();
        // 4. compute 4 K-steps
#pragma unroll
        for (int ks = 0; ks < 4; ++ks) {
            bf16x8 a[2], b[4];
#pragma unroll
            for (int mt = 0; mt < 2; ++mt) {
                const uint32_t row = (uint32_t)(wrF * 32 + mt * 16 + fr);
                a[mt] = *reinterpret_cast<const bf16x8*>(
                    smA + row * 256u +
                    (((uint32_t)(ks * 4 + h) ^ (row & 15u)) << 4));
            }
#pragma unroll
            for (int nt = 0; nt < 4; ++nt) {
                const uint32_t col = (uint32_t)(wcF * 64 + nt * 16 + fr);
                b[nt] = *reinterpret_cast<const bf16x8*>(
                    smB + col * 256u +
                    (((uint32_t)(ks * 4 + h) ^ (col & 15u)) << 4));
            }
#pragma unroll
            for (int mt = 0; mt < 2; ++mt)
#pragma unroll
                for (int nt = 0; nt < 4; ++nt)
                    facc[mt][nt] = __builtin_amdgcn_mfma_f32_16x16x32_bf16(
                        a[mt], b[nt], facc[mt][nt], 0, 0, 0);
        }
        // 5. side boundary: dump acc -> smH, rezero
        if (tk == 5 || tk == 11) {
            const int so = (tk == 11) ? 128 : 0;
#pragma unroll
            for (int nt = 0; nt < 4; ++nt) {
                const int colL = wcF * 64 + nt * 16 + fr;
                const float bv = bias[colL];
#pragma unroll
                for (int mt = 0; mt < 2; ++mt) {
#pragma unroll
                    for (int j = 0; j < 4; ++j) {
                        const int row = wrF * 32 + mt * 16 + h * 4 + j;
                        smH[row * SH + so + colL] = f2bf(facc[mt][nt][j] + bv);
                    }
                    facc[mt][nt] = (f32x4){0.f, 0.f, 0.f, 0.f};
                }
            }
        }
        asm volatile("s_waitcnt lgkmcnt(0)" ::: "memory");
        __builtin_amdgcn_sched_barrier(0);
        __builtin_amdgcn_s_barrier();
    }

    // ================= Phase 2: KAN1 GEMM (K = 256*16) =====================
    const int wrK = w >> 2, wcK = w & 3;          // 2x4 wave grid (64r x 32c)
    const int xrow = t & 127, xq = t >> 7;        // expansion: row x 2 features
    f32x4 kacc[4][2];
#pragma unroll
    for (int mt = 0; mt < 4; ++mt)
#pragma unroll
        for (int nt = 0; nt < 2; ++nt) kacc[mt][nt] = (f32x4){0.f, 0.f, 0.f, 0.f};

#pragma unroll 1
    for (int jb = 0; jb < 32; ++jb) {
        // 1. Bp tile via gload_lds (issued first; hides under expansion VALU)
#pragma unroll
        for (int j = 0; j < 4; ++j) {
            const int idx = w * 4 + j;
            const int col = idx * 4 + (l >> 4);
            gload16(&Bp[(size_t)col * 4096 + jb * 128 +
                        (((l & 15) ^ (col & 15)) << 3)],
                    smB + idx * 1024);
        }
        // 2. expand 2 features (read smH from LDS -> phi into smA, swizzled)
        {
            const uint32_t xx = *reinterpret_cast<const uint32_t*>(
                reinterpret_cast<const char*>(smH) +
                ((size_t)xrow * SH + jb * 8 + xq * 2) * 2);
#pragma unroll
            for (int e = 0; e < 2; ++e) {
                const float x =
                    bf2f((unsigned short)(e ? (xx >> 16) : (xx & 0xffffu)));
                float bs[8];
                bspline8(x, bs);
                const uint32_t w0 = pack2(silu_f(x), bs[0]);
                const uint32_t w1 = pack2(bs[1], bs[2]);
                const uint32_t w2 = pack2(bs[3], bs[4]);
                const uint32_t w3 = pack2(bs[5], bs[6]);
                const uint32_t w4 = pack2(bs[7], 0.f);
                const int f = xq * 2 + e;
                const uint32_t base = (uint32_t)xrow * 256u;
                const uint32_t s0 = (uint32_t)((2 * f) ^ (xrow & 15)) << 4;
                const uint32_t s1 = (uint32_t)((2 * f + 1) ^ (xrow & 15)) << 4;
                *reinterpret_cast<int4*>(smA + base + s0) =
                    make_int4((int)w0, (int)w1, (int)w2, (int)w3);
                *reinterpret_cast<int4*>(smA + base + s1) =
                    make_int4((int)w4, 0, 0, 0);
            }
        }
        asm volatile("s_waitcnt vmcnt(0) lgkmcnt(0)" ::: "memory");
        __builtin_amdgcn_sched_barrier(0);
        __builtin_amdgcn_s_barrier();
        // 3. compute 4 K-steps
#pragma unroll
        for (int ks = 0; ks < 4; ++ks) {
            bf16x8 a[4], b[2];
#pragma unroll
            for (int mt = 0; mt < 4; ++mt) {
                const uint32_t row = (uint32_t)(wrK * 64 + mt * 16 + fr);
                a[mt] = *reinterpret_cast<const bf16x8*>(
                    smA + row * 256u +
                    (((uint32_t)(ks * 4 + h) ^ (row & 15u)) << 4));
            }
#pragma unroll
            for (int nt = 0; nt < 2; ++nt) {
                const uint32_t col = (uint32_t)(wcK * 32 + nt * 16 + fr);
                b[nt] = *reinterpret_cast<const bf16x8*>(
                    smB + col * 256u +
                    (((uint32_t)(ks * 4 + h) ^ (col & 15u)) << 4));
            }
#pragma unroll
            for (int mt = 0; mt < 4; ++mt)
#pragma unroll
                for (int nt = 0; nt < 2; ++nt)
                    kacc[mt][nt] = __builtin_amdgcn_mfma_f32_16x16x32_bf16(
                        a[mt], b[nt], kacc[mt][nt], 0, 0, 0);
        }
        asm volatile("s_waitcnt lgkmcnt(0)" ::: "memory");
        __builtin_amdgcn_sched_barrier(0);
        __builtin_amdgcn_s_barrier();
    }

    // ================= Phase 3: KAN2 + sigmoid =============================
    unsigned short* smH2 = (unsigned short*)lds;  // reuse smA+smB area
#pragma unroll
    for (int mt = 0; mt < 4; ++mt)
#pragma unroll
        for (int nt = 0; nt < 2; ++nt) {
            const int col = wcK * 32 + nt * 16 + fr;
#pragma unroll
            for (int j = 0; j < 4; ++j) {
                const int row = wrK * 64 + mt * 16 + h * 4 + j;
                smH2[row * 136 + col] = f2bf(kacc[mt][nt][j]);
            }
        }
    __syncthreads();
    const int row2 = t >> 2, qd = t & 3;          // 4 threads/row, 32 cols each
    float sum = 0.f;
#pragma unroll 4
    for (int i = 0; i < 32; ++i) {
        const int j = qd * 32 + ((i + qd * 8) & 31);   // stagger banks
        const float x = bf2f(smH2[row2 * 136 + j]);
        float bs[8];
        bspline8(x, bs);
        const float4 s0 = *reinterpret_cast<const float4*>(&w2s[j * 8]);
        const float4 s1 = *reinterpret_cast<const float4*>(&w2s[j * 8 + 4]);
        float s = silu_f(x) * w2b[j];
        s += bs[0] * s0.x + bs[1] * s0.y + bs[2] * s0.z + bs[3] * s0.w;
        s += bs[4] * s1.x + bs[5] * s1.y + bs[6] * s1.z + bs[7] * s1.w;
        sum += s;
    }
    sum += __shfl_xor(sum, 1, 64);
    sum += __shfl_xor(sum, 2, 64);
    if (qd == 0) out[r0 + row2] = 1.0f / (1.0f + __expf(-sum));
}

// ---------------------------------------------------------------------------
extern "C" void kernel_launch(void* const* d_in, const int* in_sizes, int n_in,
                              void* d_out, int out_size, void* d_ws, size_t ws_size,
                              hipStream_t stream) {
    const float* stm  = (const float*)d_in[0];
    const float* nstm = (const float*)d_in[1];
    const float* ft_w = (const float*)d_in[2];
    const float* ft_b = (const float*)d_in[3];
    const float* k1bw = (const float*)d_in[4];
    const float* k1sw = (const float*)d_in[5];
    const float* k2bw = (const float*)d_in[6];
    const float* k2sw = (const float*)d_in[7];
    float* out = (float*)d_out;

    char* ws = (char*)d_ws;
    unsigned short* Wb = (unsigned short*)ws;                 //   196,608 B
    unsigned short* Bp = (unsigned short*)(ws + 196608);      // 1,048,576 B

    prep_ftw<<<384, 256, 0, stream>>>(ft_w, Wb);
    prep_bp<<<2048, 256, 0, stream>>>(k1bw, k1sw, Bp);
    kan_fused<<<256, 512, 0, stream>>>(stm, nstm, Wb, ft_b, Bp, k2bw, k2sw, out);
}

// Round 11
// 105.142 us; speedup vs baseline: 1.6186x; 1.0995x over previous
//
#include <hip/hip_runtime.h>
#include <hip/hip_bf16.h>
#include <math.h>
#include <stdint.h>

typedef __attribute__((ext_vector_type(8))) short bf16x8;
typedef __attribute__((ext_vector_type(4))) float f32x4;

__device__ __forceinline__ uint32_t pack2(float a, float b) {
    union { __hip_bfloat162 h2; uint32_t u; } c;
    c.h2 = __float22bfloat162_rn(make_float2(a, b));   // v_cvt_pk_bf16_f32
    return c.u;
}
__device__ __forceinline__ unsigned short f2bf(float f) {
    union { __hip_bfloat16 h; unsigned short u; } c;
    c.h = __float2bfloat16(f);
    return c.u;
}
__device__ __forceinline__ float bf2f(unsigned short h) {
    union { uint32_t u; float f; } c; c.u = ((uint32_t)h) << 16;
    return c.f;
}
__device__ __forceinline__ float silu_f(float x) {
    return x / (1.0f + __expf(-x));
}

// Uniform cardinal cubic B-spline bases on grid g_i = -2.2 + 0.4*i.
// Identical to the reference Cox-de-Boor recursion on this uniform grid.
__device__ __forceinline__ void bspline8(float x, float* __restrict__ b) {
    const float tt = (x + 2.2f) * 2.5f;
#pragma unroll
    for (int v = 0; v < 8; ++v) {
        float y = fabsf(tt - (float)(v + 2));
        float p = fmaxf(2.0f - y, 0.0f);
        float q = fmaxf(1.0f - y, 0.0f);
        b[v] = (p * p * p - 4.0f * q * q * q) * (1.0f / 6.0f);
    }
}

__device__ __forceinline__ void gload16(const void* g, void* l) {
    __builtin_amdgcn_global_load_lds(
        (const __attribute__((address_space(1))) void*)g,
        (__attribute__((address_space(3))) void*)l, 16, 0, 0);
}

// ---------------------------------------------------------------------------
// prep kernels
// ---------------------------------------------------------------------------
__global__ __launch_bounds__(256) void prep_ftw(const float* __restrict__ ftw,
                                                unsigned short* __restrict__ Wb) {
    const int idx = blockIdx.x * 256 + threadIdx.x;   // 98304 = 128*768
    Wb[idx] = f2bf(ftw[idx]);
}

__global__ __launch_bounds__(256) void prep_bp(const float* __restrict__ bw,
                                               const float* __restrict__ sw,
                                               unsigned short* __restrict__ Bp) {
    const int idx = blockIdx.x * 256 + threadIdx.x;   // 524288 = 128*4096
    const int n = idx >> 12;
    const int k = idx & 4095;
    const int f = k >> 4;
    const int v = k & 15;
    float val = 0.f;
    if (v == 0) val = bw[n * 256 + f];
    else if (v <= 8) val = sw[(size_t)(n * 256 + f) * 8 + (v - 1)];
    Bp[idx] = f2bf(val);
}

// ---------------------------------------------------------------------------
// FUSED, BM=64, 2 blocks/CU (LDS exactly 80 KB).  Per 64-row tile:
//   Phase 1: FT GEMM both sides (12 BK=128 tiles), depth-2 reg prefetch of A
//            (named reg sets, counted vmcnt(4)), Wb via gload_lds with
//            pre-swizzled source (rule 21).  H -> smHT (transposed
//            [256 feat][64 rows] bf16, chunk-XOR swizzled) -- LDS only.
//   Phase 2: KAN1 expanded-A GEMM, 32 jb-steps; Bp gloads issued first,
//            expansion VALU hides their L2 latency; conflict-free smHT read.
//   Phase 3: KAN2 reduce + sigmoid.
// grid 512, block 512 (8 waves as 2x4; wave tile 32r x 32c both GEMMs).
// ---------------------------------------------------------------------------
__global__ __launch_bounds__(512, 4) void kan_fused(
        const float* __restrict__ stm, const float* __restrict__ nstm,
        const unsigned short* __restrict__ Wb, const float* __restrict__ bias,
        const unsigned short* __restrict__ Bp,
        const float* __restrict__ w2b, const float* __restrict__ w2s,
        float* __restrict__ out) {
    __shared__ alignas(16) char lds[81920];
    char* smA  = lds;            // 16 KB: A/phi tile 64 x 128 bf16, swizzled
    char* smB  = lds + 16384;    // 32 KB: B tile 128 x 128 bf16, swizzled
    char* smHT = lds + 49152;    // 32 KB: H^T [256 feat][64 rows] bf16, swizzled

    const int r0 = blockIdx.x * 64;
    const int t = threadIdx.x;
    const int l = t & 63, w = t >> 6;
    const int fr = l & 15, h = l >> 4;
    const int wr = w >> 2, wc = w & 3;        // 2x4 wave grid, tile 32r x 32c

    // A staging geometry: thread -> row (t>>3), 16 floats at col (t&7)*16
    const int arow = t >> 3;
    const int acol = (t & 7) * 16;
    const uint32_t adst0 = (uint32_t)arow * 256u +
        ((uint32_t)(((t & 7) * 2) ^ (arow & 15)) << 4);
    const uint32_t adst1 = (uint32_t)arow * 256u +
        ((uint32_t)(((t & 7) * 2 + 1) ^ (arow & 15)) << 4);
    const int gidx = w * 4;                   // gload instr base index

    f32x4 acc[2][2];
#pragma unroll
    for (int mt = 0; mt < 2; ++mt)
#pragma unroll
        for (int nt = 0; nt < 2; ++nt) acc[mt][nt] = (f32x4){0.f, 0.f, 0.f, 0.f};

    float4 regY[4], regZ[4];

#define FT_ISSUE(REG, TK)                                                      \
    {                                                                          \
        const float* __restrict__ Ap = ((TK) >= 6) ? nstm : stm;               \
        const int kk = ((TK) % 6) * 128;                                       \
        _Pragma("unroll") for (int q = 0; q < 4; ++q)                          \
            REG[q] = *reinterpret_cast<const float4*>(                         \
                &Ap[(size_t)(r0 + arow) * 768 + kk + acol + q * 4]);           \
    }

#define FT_WRITE(REG)                                                          \
    {                                                                          \
        int4 w0, w1;                                                           \
        w0.x = (int)pack2(REG[0].x, REG[0].y);                                 \
        w0.y = (int)pack2(REG[0].z, REG[0].w);                                 \
        w0.z = (int)pack2(REG[1].x, REG[1].y);                                 \
        w0.w = (int)pack2(REG[1].z, REG[1].w);                                 \
        w1.x = (int)pack2(REG[2].x, REG[2].y);                                 \
        w1.y = (int)pack2(REG[2].z, REG[2].w);                                 \
        w1.z = (int)pack2(REG[3].x, REG[3].y);                                 \
        w1.w = (int)pack2(REG[3].z, REG[3].w);                                 \
        *reinterpret_cast<int4*>(smA + adst0) = w0;                            \
        *reinterpret_cast<int4*>(smA + adst1) = w1;                            \
    }

#define GLOADB_FT(K0)                                                          \
    _Pragma("unroll") for (int j = 0; j < 4; ++j) {                            \
        const int col = (gidx + j) * 4 + (l >> 4);                             \
        gload16(&Wb[(size_t)col * 768 + (K0) + (((l & 15) ^ (col & 15)) << 3)],\
                smB + (gidx + j) * 1024);                                      \
    }

#define GEMM_STEP()                                                            \
    _Pragma("unroll") for (int ks = 0; ks < 4; ++ks) {                         \
        bf16x8 a[2], b[2];                                                     \
        _Pragma("unroll") for (int mt = 0; mt < 2; ++mt) {                     \
            const uint32_t row = (uint32_t)(wr * 32 + mt * 16 + fr);           \
            a[mt] = *reinterpret_cast<const bf16x8*>(                          \
                smA + row * 256u +                                             \
                (((uint32_t)(ks * 4 + h) ^ (row & 15u)) << 4));                \
        }                                                                      \
        _Pragma("unroll") for (int nt = 0; nt < 2; ++nt) {                     \
            const uint32_t col = (uint32_t)(wc * 32 + nt * 16 + fr);           \
            b[nt] = *reinterpret_cast<const bf16x8*>(                          \
                smB + col * 256u +                                             \
                (((uint32_t)(ks * 4 + h) ^ (col & 15u)) << 4));                \
        }                                                                      \
        _Pragma("unroll") for (int mt = 0; mt < 2; ++mt)                       \
            _Pragma("unroll") for (int nt = 0; nt < 2; ++nt)                   \
                acc[mt][nt] = __builtin_amdgcn_mfma_f32_16x16x32_bf16(         \
                    a[mt], b[nt], acc[mt][nt], 0, 0, 0);                       \
    }

#define DUMP_H(SO)                                                             \
    _Pragma("unroll") for (int nt = 0; nt < 2; ++nt) {                         \
        const int col = wc * 32 + nt * 16 + fr;                                \
        const float bv = bias[col];                                            \
        const int feat = (SO) + col;                                           \
        _Pragma("unroll") for (int mt = 0; mt < 2; ++mt) {                     \
            const int rowb = wr * 32 + mt * 16 + h * 4;                        \
            int2 o;                                                            \
            o.x = (int)pack2(acc[mt][nt][0] + bv, acc[mt][nt][1] + bv);        \
            o.y = (int)pack2(acc[mt][nt][2] + bv, acc[mt][nt][3] + bv);        \
            const uint32_t db = (uint32_t)feat * 128u +                        \
                ((uint32_t)((rowb >> 3) ^ (feat & 7)) << 4) +                  \
                (uint32_t)(rowb & 7) * 2u;                                     \
            *reinterpret_cast<int2*>(smHT + db) = o;                           \
            acc[mt][nt] = (f32x4){0.f, 0.f, 0.f, 0.f};                         \
        }                                                                      \
    }

#define LGKM_BAR()                                                             \
    asm volatile("s_waitcnt lgkmcnt(0)" ::: "memory");                         \
    __builtin_amdgcn_sched_barrier(0);                                         \
    __builtin_amdgcn_s_barrier();

    // ================= Phase 1: feature transform (both sides) =============
    FT_ISSUE(regY, 0);
    FT_ISSUE(regZ, 1);
#pragma unroll 1
    for (int pp = 0; pp < 6; ++pp) {
        // ---- even slot: tile 2pp ----
        FT_WRITE(regY);                       // compiler waits regY's loads
        GLOADB_FT(((2 * pp) % 6) * 128);
        __builtin_amdgcn_sched_barrier(0);    // pin: B gloads older than A issue
        if (pp < 5) {
            FT_ISSUE(regY, 2 * pp + 2);
            asm volatile("s_waitcnt vmcnt(4)" ::: "memory");   // B done, A flying
        } else {
            asm volatile("s_waitcnt vmcnt(0)" ::: "memory");
        }
        asm volatile("s_waitcnt lgkmcnt(0)" ::: "memory");
        __builtin_amdgcn_sched_barrier(0);
        __builtin_amdgcn_s_barrier();
        __builtin_amdgcn_s_setprio(1);
        GEMM_STEP();
        __builtin_amdgcn_s_setprio(0);
        LGKM_BAR();
        // ---- odd slot: tile 2pp+1 ----
        FT_WRITE(regZ);
        GLOADB_FT(((2 * pp + 1) % 6) * 128);
        __builtin_amdgcn_sched_barrier(0);
        if (pp < 5) {
            FT_ISSUE(regZ, 2 * pp + 3);
            asm volatile("s_waitcnt vmcnt(4)" ::: "memory");
        } else {
            asm volatile("s_waitcnt vmcnt(0)" ::: "memory");
        }
        asm volatile("s_waitcnt lgkmcnt(0)" ::: "memory");
        __builtin_amdgcn_sched_barrier(0);
        __builtin_amdgcn_s_barrier();
        __builtin_amdgcn_s_setprio(1);
        GEMM_STEP();
        __builtin_amdgcn_s_setprio(0);
        if (pp == 2) { DUMP_H(0); }           // side 0 complete
        if (pp == 5) { DUMP_H(128); }         // side 1 complete
        LGKM_BAR();
    }

    // ================= Phase 2: KAN1 GEMM (K = 256*16) =====================
#pragma unroll 1
    for (int jb = 0; jb < 32; ++jb) {
        // 1. Bp tile gloads first (L2 latency hides under expansion VALU)
#pragma unroll
        for (int j = 0; j < 4; ++j) {
            const int col = (gidx + j) * 4 + (l >> 4);
            gload16(&Bp[(size_t)col * 4096 + jb * 128 +
                        (((l & 15) ^ (col & 15)) << 3)],
                    smB + (gidx + j) * 1024);
        }
        __builtin_amdgcn_sched_barrier(0);
        // 2. expansion: wave w -> feature jb*8+w, lane l -> row l
        {
            const int feat = jb * 8 + w;
            const unsigned short xv = *reinterpret_cast<const unsigned short*>(
                smHT + (uint32_t)feat * 128u +
                ((uint32_t)((l >> 3) ^ (feat & 7)) << 4) + (uint32_t)(l & 7) * 2u);
            const float x = bf2f(xv);
            float bs[8];
            bspline8(x, bs);
            const uint32_t pw0 = pack2(silu_f(x), bs[0]);
            const uint32_t pw1 = pack2(bs[1], bs[2]);
            const uint32_t pw2 = pack2(bs[3], bs[4]);
            const uint32_t pw3 = pack2(bs[5], bs[6]);
            const uint32_t pw4 = pack2(bs[7], 0.f);
            const uint32_t d0 = (uint32_t)l * 256u +
                ((uint32_t)((2 * w) ^ (l & 15)) << 4);
            const uint32_t d1 = (uint32_t)l * 256u +
                ((uint32_t)((2 * w + 1) ^ (l & 15)) << 4);
            *reinterpret_cast<int4*>(smA + d0) =
                make_int4((int)pw0, (int)pw1, (int)pw2, (int)pw3);
            *reinterpret_cast<int4*>(smA + d1) = make_int4((int)pw4, 0, 0, 0);
        }
        asm volatile("s_waitcnt vmcnt(0) lgkmcnt(0)" ::: "memory");
        __builtin_amdgcn_sched_barrier(0);
        __builtin_amdgcn_s_barrier();
        __builtin_amdgcn_s_setprio(1);
        GEMM_STEP();
        __builtin_amdgcn_s_setprio(0);
        LGKM_BAR();
    }

    // ================= Phase 3: KAN2 + sigmoid =============================
    unsigned short* smH2 = (unsigned short*)lds;   // reuse smA/smB region
#pragma unroll
    for (int mt = 0; mt < 2; ++mt)
#pragma unroll
        for (int nt = 0; nt < 2; ++nt) {
            const int col = wc * 32 + nt * 16 + fr;
#pragma unroll
            for (int j = 0; j < 4; ++j) {
                const int row = wr * 32 + mt * 16 + h * 4 + j;
                smH2[row * 136 + col] = f2bf(acc[mt][nt][j]);
            }
        }
    __syncthreads();
    const int row2 = t >> 3, qd = t & 7;           // 8 threads/row, 16 cols each
    float sum = 0.f;
#pragma unroll 4
    for (int i = 0; i < 16; ++i) {
        const int j = qd * 16 + ((i + qd * 2) & 15);   // stagger banks
        const float x = bf2f(smH2[row2 * 136 + j]);
        float bs[8];
        bspline8(x, bs);
        const float4 s0 = *reinterpret_cast<const float4*>(&w2s[j * 8]);
        const float4 s1 = *reinterpret_cast<const float4*>(&w2s[j * 8 + 4]);
        float s = silu_f(x) * w2b[j];
        s += bs[0] * s0.x + bs[1] * s0.y + bs[2] * s0.z + bs[3] * s0.w;
        s += bs[4] * s1.x + bs[5] * s1.y + bs[6] * s1.z + bs[7] * s1.w;
        sum += s;
    }
    sum += __shfl_xor(sum, 1, 64);
    sum += __shfl_xor(sum, 2, 64);
    sum += __shfl_xor(sum, 4, 64);
    if (qd == 0) out[r0 + row2] = 1.0f / (1.0f + __expf(-sum));
}

// ---------------------------------------------------------------------------
extern "C" void kernel_launch(void* const* d_in, const int* in_sizes, int n_in,
                              void* d_out, int out_size, void* d_ws, size_t ws_size,
                              hipStream_t stream) {
    const float* stm  = (const float*)d_in[0];
    const float* nstm = (const float*)d_in[1];
    const float* ft_w = (const float*)d_in[2];
    const float* ft_b = (const float*)d_in[3];
    const float* k1bw = (const float*)d_in[4];
    const float* k1sw = (const float*)d_in[5];
    const float* k2bw = (const float*)d_in[6];
    const float* k2sw = (const float*)d_in[7];
    float* out = (float*)d_out;

    char* ws = (char*)d_ws;
    unsigned short* Wb = (unsigned short*)ws;                 //   196,608 B
    unsigned short* Bp = (unsigned short*)(ws + 196608);      // 1,048,576 B

    prep_ftw<<<384, 256, 0, stream>>>(ft_w, Wb);
    prep_bp<<<2048, 256, 0, stream>>>(k1bw, k1sw, Bp);
    kan_fused<<<512, 512, 0, stream>>>(stm, nstm, Wb, ft_b, Bp, k2bw, k2sw, out);
}